// Round 1
// baseline (89.304 us; speedup 1.0000x reference)
//
#include <hip/hip_runtime.h>

#define NBINS 256
#define NWAVES 4   // 256 threads / 64 lanes

__global__ void zero_out_kernel(float* __restrict__ out) {
    out[threadIdx.x] = 0.0f;
}

__global__ __launch_bounds__(256) void hist_kernel(const float* __restrict__ x,
                                                   float* __restrict__ out,
                                                   int n) {
    __shared__ int lh[NWAVES][NBINS];
    const int tid  = threadIdx.x;
    const int wave = tid >> 6;

    // zero LDS histograms
    #pragma unroll
    for (int i = tid; i < NWAVES * NBINS; i += 256)
        ((int*)lh)[i] = 0;
    __syncthreads();

    const int gid    = blockIdx.x * 256 + tid;
    const int stride = gridDim.x * 256;

    const int n4 = n >> 2;  // float4 count
    const float4* __restrict__ x4 = (const float4*)x;

    for (int i = gid; i < n4; i += stride) {
        float4 v = x4[i];
        float vals[4] = {v.x, v.y, v.z, v.w};
        #pragma unroll
        for (int j = 0; j < 4; ++j) {
            float f = vals[j];
            // in-range check: [-4, 4] inclusive; NaN fails -> dropped
            if (f >= -4.0f && f <= 4.0f) {
                // width = 8/256 = 0.03125 exactly; *32 == /width exactly
                int b = (int)floorf((f + 4.0f) * 32.0f);
                b = b > (NBINS - 1) ? (NBINS - 1) : b;  // x == 4 -> last bin
                atomicAdd(&lh[wave][b], 1);
            }
        }
    }

    // scalar tail (n not divisible by 4 — not hit for N=64M, kept for safety)
    for (int i = (n4 << 2) + gid; i < n; i += stride) {
        float f = x[i];
        if (f >= -4.0f && f <= 4.0f) {
            int b = (int)floorf((f + 4.0f) * 32.0f);
            b = b > (NBINS - 1) ? (NBINS - 1) : b;
            atomicAdd(&lh[wave][b], 1);
        }
    }

    __syncthreads();

    // flush: one float atomic per bin per block; integer-valued floats < 2^24
    // => exact, order-independent, deterministic.
    int s = lh[0][tid] + lh[1][tid] + lh[2][tid] + lh[3][tid];
    if (s)
        atomicAdd(&out[tid], (float)s);
}

extern "C" void kernel_launch(void* const* d_in, const int* in_sizes, int n_in,
                              void* d_out, int out_size, void* d_ws, size_t ws_size,
                              hipStream_t stream) {
    const float* x = (const float*)d_in[0];
    float* out = (float*)d_out;
    const int n = in_sizes[0];

    // d_out is poisoned before timing and not re-zeroed between replays:
    // zero it ourselves every call (stream-ordered before hist).
    zero_out_kernel<<<1, NBINS, 0, stream>>>(out);

    int n4 = n >> 2;
    int blocks = (n4 + 255) / 256;
    if (blocks > 2048) blocks = 2048;
    if (blocks < 1) blocks = 1;
    hist_kernel<<<blocks, 256, 0, stream>>>(x, out, n);
}

// Round 2
// 88.391 us; speedup vs baseline: 1.0103x; 1.0103x over previous
//
#include <hip/hip_runtime.h>

#define NBINS 256
#define NCOPY 16      // one histogram copy per 16-lane group
#define CSTRIDE 257   // bank-rotated copies: (c*257 + b) % 32 == (c + b) % 32

__global__ void zero_out_kernel(float* __restrict__ out) {
    out[threadIdx.x] = 0.0f;
}

__global__ __launch_bounds__(256) void hist_kernel(const float* __restrict__ x,
                                                   float* __restrict__ out,
                                                   int n) {
    __shared__ int lh[NCOPY * CSTRIDE];
    const int tid = threadIdx.x;
    // copy id = (wave<<2) | (lane>>4)  ==  tid>>4 for 256 threads
    int* __restrict__ myh = &lh[(tid >> 4) * CSTRIDE];

    for (int i = tid; i < NCOPY * CSTRIDE; i += 256)
        lh[i] = 0;
    __syncthreads();

    const int gid    = blockIdx.x * 256 + tid;
    const int stride = gridDim.x * 256;
    const int n4     = n >> 2;
    const float4* __restrict__ x4 = (const float4*)x;

    // bin math matches reference exactly: width = 8/256 = 0.03125 (exact pow2),
    // so floor((x-lo)/width) == floor((x+4)*32); the in-range value is >= 0 so
    // int-trunc == floor. x == 4 -> 256 -> clamped to 255. NaN fails the range
    // test -> dropped.
#define PROC(f) do {                                    \
        float _t = ((f) + 4.0f) * 32.0f;                \
        if ((f) >= -4.0f && (f) <= 4.0f) {              \
            int _b = (int)_t;                           \
            _b = _b > (NBINS - 1) ? (NBINS - 1) : _b;   \
            atomicAdd(&myh[_b], 1);                     \
        }                                               \
    } while (0)

    int i = gid;
    for (; i + stride < n4; i += 2 * stride) {
        float4 a = x4[i];
        float4 b = x4[i + stride];
        PROC(a.x); PROC(a.y); PROC(a.z); PROC(a.w);
        PROC(b.x); PROC(b.y); PROC(b.z); PROC(b.w);
    }
    if (i < n4) {
        float4 a = x4[i];
        PROC(a.x); PROC(a.y); PROC(a.z); PROC(a.w);
    }

    // scalar tail (n not divisible by 4 — not hit for N=64M)
    for (int j = (n4 << 2) + gid; j < n; j += stride) {
        float f = x[j];
        PROC(f);
    }
#undef PROC

    __syncthreads();

    // flush: bin `tid` summed across 16 copies; reads are 2-way bank aliased
    // (free). One float atomic per bin per block; per-bin totals < 2^24 so
    // float adds are exact and order-independent -> deterministic.
    int s = 0;
    #pragma unroll
    for (int c = 0; c < NCOPY; ++c)
        s += lh[c * CSTRIDE + tid];
    if (s)
        atomicAdd(&out[tid], (float)s);
}

extern "C" void kernel_launch(void* const* d_in, const int* in_sizes, int n_in,
                              void* d_out, int out_size, void* d_ws, size_t ws_size,
                              hipStream_t stream) {
    const float* x = (const float*)d_in[0];
    float* out = (float*)d_out;
    const int n = in_sizes[0];

    // d_out is poisoned before timing and not re-zeroed between replays:
    // zero it ourselves every call (stream-ordered before hist).
    zero_out_kernel<<<1, NBINS, 0, stream>>>(out);

    int n4 = n >> 2;
    int blocks = (n4 + 255) / 256;
    if (blocks > 2048) blocks = 2048;
    if (blocks < 1) blocks = 1;
    hist_kernel<<<blocks, 256, 0, stream>>>(x, out, n);
}